// Round 14
// baseline (164.132 us; speedup 1.0000x reference)
//
#include <hip/hip_runtime.h>
#include <math.h>

// Problem constants (fixed by setup_inputs)
constexpr int B_ = 8;
constexpr int N_ = 16384;
constexpr int M_ = 1024;
constexpr int C_ = 256;
constexpr int NCHUNK = 8;
constexpr int CHUNK = M_ / NCHUNK;  // 128
constexpr int KEEP = 4;             // per-chunk survivors
constexpr int TOPK_BLOCK = 1024;    // 16 waves/block -> 2 blocks/CU -> 2 K$ streams

// Calibration ledger (R11 probe + R12/R13 deltas):
//   topk ~37us (VALU-issue + ~20us fixed: SMEM latency/tail/clock),
//   gather ~22-25us (write floor), prep ~4, merge ~3.5, gaps ~2-3 each.
// R12 lesson: v_pk_*_f32 double-pumps the SIMD-32 FP32 ALU -> pk is
// issue-equivalent to 2 scalar ops; only REAL op removal buys time
// (~1.0us per equiv-op/pair removed, R12/R13 measured).
// R14: fuse merge into gather AT GATHER'S PROVEN GRID (32768 blocks,
// 4 pts/block) -- avoids R4's grid collapse and R7's butterfly cost.
// Saves merge dispatch + 1 gap + idx/w round-trip.

// native vectors (clang ext_vector): float2 for packed-fp32 math, float4
// for __builtin_nontemporal_store (HIP's float4 class is rejected there).
typedef float f32x2 __attribute__((ext_vector_type(2)));
typedef float nfloat4 __attribute__((ext_vector_type(4)));

// 4-deep sorted-insert network (P0<=P1<=P2<=P3 invariant); valid for any
// non-NaN floats incl. negatives. min + 3x v_med3_f32, all VOP3-legal.
#define INSERT4(P, u)                                              \
  {                                                                \
    const float o0 = P##0, o1 = P##1, o2 = P##2;                   \
    P##0 = fminf(o0, (u));                                         \
    P##1 = __builtin_amdgcn_fmed3f(o0, P##1, (u));                 \
    P##2 = __builtin_amdgcn_fmed3f(o1, P##2, (u));                 \
    P##3 = __builtin_amdgcn_fmed3f(o2, P##3, (u));                 \
  }

// ---------------------------------------------------------------------------
// Kernel 0 (fused prep): blocks [0,32) pack centroids; blocks [32, 32+2048)
// transpose centroid_f [B,C,M] -> fT [B,M,C] via 32x32 LDS tiles (+1 pad).
// ---------------------------------------------------------------------------
__global__ __launch_bounds__(256) void prep_kernel(
    const float* __restrict__ cxyz,  // [B, M, 3]
    const float* __restrict__ cf,    // [B, C, M]
    float* __restrict__ csoa,        // [B][NCHUNK][CHUNK/2][8]
    float4* __restrict__ cpack,      // [B*M]
    float* __restrict__ fT)          // [B, M, C]
{
  __shared__ float tile[32][33];
  const int tx = threadIdx.x;  // 0..31
  const int ty = threadIdx.y;  // 0..7
  if (blockIdx.x < 32) {
    // ---- pack role ----
    const int i = blockIdx.x * 256 + (ty * 32 + tx);  // global centroid id
    if (i < B_ * M_) {
      const int b = i >> 10;         // / M_
      const int m = i & (M_ - 1);
      const int chunk = m >> 7;      // / CHUNK
      const int mi = m & (CHUNK - 1);
      const int pair = mi >> 1;
      const int sub = mi & 1;
      const float x = cxyz[3 * i + 0];
      const float y = cxyz[3 * i + 1];
      const float z = cxyz[3 * i + 2];
      const float w = x * x + y * y + z * z;
      float* pb = csoa + ((((size_t)b * NCHUNK + chunk) * (CHUNK / 2)) + pair) * 8 + sub;
      pb[0] = x; pb[2] = y; pb[4] = z; pb[6] = w;
      cpack[i] = make_float4(x, y, z, w);
    }
  } else {
    // ---- transpose role ----
    const int bid = blockIdx.x - 32;       // 0..2047
    const int m0 = (bid & 31) * 32;        // M/32 = 32
    const int c0 = ((bid >> 5) & 7) * 32;  // C/32 = 8
    const int b = bid >> 8;
    const float* fb = cf + (size_t)b * C_ * M_;
    float* ftb = fT + (size_t)b * M_ * C_;
#pragma unroll
    for (int j = 0; j < 32; j += 8)
      tile[ty + j][tx] = fb[(size_t)(c0 + ty + j) * M_ + (m0 + tx)];
    __syncthreads();
#pragma unroll
    for (int j = 0; j < 32; j += 8)
      ftb[(size_t)(m0 + ty + j) * C_ + (c0 + tx)] = tile[tx][ty + j];
  }
}

// ---------------------------------------------------------------------------
// Kernel 1: chunked top-4 -- VERBATIM R13 (best: 82.4us).
//   key = |c|^2 - 2x.c  (3 pk_fma from cw; rank-equivalent to d^2)
//   index pack via v_bfi_b32 (mask VGPR, index SGPR -> 1 SGPR operand)
//   per pair: 3 pk + 2 bfi + 8 min/med3 = 16 equiv-ops.
// DO NOT fuse other roles into this kernel (R1/R2 lesson).
// ---------------------------------------------------------------------------
__global__ __launch_bounds__(TOPK_BLOCK) void topk_chunk_kernel(
    const float* __restrict__ xyz,   // [B, N, 3]
    const float* __restrict__ csoa,  // [B][NCHUNK][CHUNK/2][8]
    unsigned* __restrict__ cand)     // [B*N][NCHUNK]: 4 packed 8-bit indices
{
  const int b = blockIdx.z;
  const int chunk = blockIdx.y;
  const int n = blockIdx.x * TOPK_BLOCK + threadIdx.x;
  const size_t p = (size_t)b * N_ + n;

  const f32x2* __restrict__ cb2 = (const f32x2*)(
      csoa + (((size_t)b * NCHUNK + chunk) * (CHUNK / 2)) * 8);

  const float* xp = xyz + p * 3;
  const float x0 = xp[0], x1 = xp[1], x2 = xp[2];
  const f32x2 nx0_2 = {-2.f * x0, -2.f * x0};
  const f32x2 nx1_2 = {-2.f * x1, -2.f * x1};
  const f32x2 nx2_2 = {-2.f * x2, -2.f * x2};
  unsigned maskv = 0xFFFFFF80u;  // "v"-constrained -> hoisted VGPR constant

  float A0 = INFINITY, A1 = INFINITY, A2 = INFINITY, A3 = INFINITY;
  float B0 = INFINITY, B1 = INFINITY, B2 = INFINITY, B3 = INFINITY;

#pragma unroll 8
  for (int i = 0; i < CHUNK / 2; ++i) {
    // {x0,x1},{y0,y1},{z0,z1},{w0,w1} -- one packed operand per 8B pair
    const f32x2 cx = cb2[i * 4 + 0];
    const f32x2 cy = cb2[i * 4 + 1];
    const f32x2 cz = cb2[i * 4 + 2];
    const f32x2 cw = cb2[i * 4 + 3];

    // key = |c|^2 - 2 x.c  (3 pk_fma; rank-equivalent to d^2 per point)
    f32x2 t = __builtin_elementwise_fma(nx0_2, cx, cw);
    t = __builtin_elementwise_fma(nx1_2, cy, t);
    t = __builtin_elementwise_fma(nx2_2, cz, t);

    // pack 7-bit local index into low mantissa bits: one v_bfi_b32 per key
    unsigned kxu, kyu;
    asm("v_bfi_b32 %0, %1, %2, %3"
        : "=v"(kxu)
        : "v"(maskv), "v"(__float_as_uint(t.x)), "s"((unsigned)(2 * i)));
    asm("v_bfi_b32 %0, %1, %2, %3"
        : "=v"(kyu)
        : "v"(maskv), "v"(__float_as_uint(t.y)), "s"((unsigned)(2 * i + 1)));
    const float kx = __uint_as_float(kxu);
    const float ky = __uint_as_float(kyu);
    INSERT4(A, kx);
    INSERT4(B, ky);
  }
  // fold chain B into chain A (exact running-inserts)
  INSERT4(A, B0);
  INSERT4(A, B1);
  INSERT4(A, B2);
  INSERT4(A, B3);

  const unsigned i0 = __float_as_uint(A0) & 127u;
  const unsigned i1 = __float_as_uint(A1) & 127u;
  const unsigned i2 = __float_as_uint(A2) & 127u;
  const unsigned i3 = __float_as_uint(A3) & 127u;
  cand[p * NCHUNK + chunk] = i0 | (i1 << 8) | (i2 << 16) | (i3 << 24);
}

// ---------------------------------------------------------------------------
// Kernel 2 (fused merge+gather at GATHER'S PROVEN GRID -- fixes both prior
// fusion failures: R4 collapsed the grid 64x, R7 used a 7x-cost butterfly):
// 32768 blocks x 256 threads, 4 points/block.
//   Phase A: threads 0..3 each run the VERBATIM serial merge for one point
//     (f64 re-rank kd = |c|^2 - 2x.c, stable strict-< insertion, same scan
//     order -> bit-identical selection + weights). 32 independent cpack
//     loads unroll; other lanes exec-masked for this short phase.
//   Phase B: verbatim R5 gather -- wave-per-point (4 waves = 4 points),
//     fT rows 1KB coalesced, batch<->XCD swizzle, nt stores.
// Saves: merge dispatch (~3.5us) + 1 launch gap + 1.5MB idx/w round-trip.
// ---------------------------------------------------------------------------
__global__ __launch_bounds__(256) void mg_kernel(
    const float* __restrict__ xyz,     // [B, N, 3]
    const float4* __restrict__ cpack,  // [B*M]
    const unsigned* __restrict__ cand, // [B*N][NCHUNK]
    const float* __restrict__ fT,      // [B, M, C]
    float* __restrict__ out)           // [B, N, C]
{
  __shared__ int   sI[4 * 3];
  __shared__ float sW[4 * 3];
  const int tid = threadIdx.x;
  // batch<->XCD swizzle: 32768 groups of 4 points; 4096 groups per batch.
  const int g = ((int)blockIdx.x & 7) * 4096 + ((int)blockIdx.x >> 3);
  const size_t pbase = (size_t)g * 4;
  const int b = (int)(pbase >> 14);  // == blockIdx.x & 7

  if (tid < 4) {
    // ---- Phase A: serial merge, verbatim proven merge_kernel body ----
    const size_t p = pbase + tid;
    const float* xp = xyz + p * 3;
    const double x0d = (double)xp[0], x1d = (double)xp[1], x2d = (double)xp[2];
    const float4* __restrict__ cb = cpack + (size_t)b * M_;

    const uint4* cw4 = (const uint4*)(cand + p * NCHUNK);
    const uint4 ca = cw4[0], cb2 = cw4[1];
    unsigned words[NCHUNK] = {ca.x, ca.y, ca.z, ca.w, cb2.x, cb2.y, cb2.z, cb2.w};

    double D0 = 1e300, D1 = 1e300, D2 = 1e300;
    int I0 = 0, I1 = 0, I2 = 0;
#pragma unroll
    for (int ch = 0; ch < NCHUNK; ++ch) {
      const unsigned w = words[ch];
#pragma unroll
      for (int j = 0; j < KEEP; ++j) {
        const int m = ch * CHUNK + (int)((w >> (8 * j)) & 255u);
        const float4 c = cb[m];
        const double cx = (double)c.x, cy = (double)c.y, cz = (double)c.z;
        const double dot = x0d * cx + x1d * cy + x2d * cz;
        const double c2d = cx * cx + cy * cy + cz * cz;
        const double kd = c2d - 2.0 * dot;
        if (kd < D2) {
          if (kd < D1) {
            D2 = D1; I2 = I1;
            if (kd < D0) { D1 = D0; I1 = I0; D0 = kd; I0 = m; }
            else         { D1 = kd; I1 = m; }
          } else {
            D2 = kd; I2 = m;
          }
        }
      }
    }

    const double xx = x0d * x0d + x1d * x1d + x2d * x2d;
    const float d0 = sqrtf(fmaxf((float)(xx + D0), 0.0f));
    const float d1 = sqrtf(fmaxf((float)(xx + D1), 0.0f));
    const float d2 = sqrtf(fmaxf((float)(xx + D2), 0.0f));
    float w0 = 1.0f / fmaxf(d0, 1e-8f);
    float w1 = 1.0f / fmaxf(d1, 1e-8f);
    float w2 = 1.0f / fmaxf(d2, 1e-8f);
    const float wsum = w0 + w1 + w2;
    w0 /= wsum; w1 /= wsum; w2 /= wsum;

    sI[tid * 3 + 0] = I0; sI[tid * 3 + 1] = I1; sI[tid * 3 + 2] = I2;
    sW[tid * 3 + 0] = w0; sW[tid * 3 + 1] = w1; sW[tid * 3 + 2] = w2;
  }
  __syncthreads();

  // ---- Phase B: gather, verbatim R5 pattern (wave-per-point, nt store) ----
  const int wid  = tid >> 6;
  const int lane = tid & 63;
  const size_t p = pbase + wid;
  const int i0 = sI[wid * 3 + 0], i1 = sI[wid * 3 + 1], i2 = sI[wid * 3 + 2];
  const float w0 = sW[wid * 3 + 0], w1 = sW[wid * 3 + 1], w2 = sW[wid * 3 + 2];

  const float4* f4 = (const float4*)(fT + (size_t)b * M_ * C_);
  float4 a  = f4[(size_t)i0 * (C_ / 4) + lane];
  float4 bb = f4[(size_t)i1 * (C_ / 4) + lane];
  float4 c  = f4[(size_t)i2 * (C_ / 4) + lane];

  nfloat4 r;
  r.x = w0 * a.x + w1 * bb.x + w2 * c.x;
  r.y = w0 * a.y + w1 * bb.y + w2 * c.y;
  r.z = w0 * a.z + w1 * bb.z + w2 * c.z;
  r.w = w0 * a.w + w1 * bb.w + w2 * c.w;

  __builtin_nontemporal_store(r, &((nfloat4*)out)[p * (C_ / 4) + lane]);
}

extern "C" void kernel_launch(void* const* d_in, const int* in_sizes, int n_in,
                              void* d_out, int out_size, void* d_ws, size_t ws_size,
                              hipStream_t stream) {
  const float* xyz  = (const float*)d_in[0];  // [B, N, 3]
  const float* cxyz = (const float*)d_in[1];  // [B, M, 3]
  const float* cf   = (const float*)d_in[2];  // [B, C, M]
  float* out = (float*)d_out;                 // [B, N, C]

  char* ws = (char*)d_ws;
  const size_t npts = (size_t)B_ * N_;

  float4* cpack = (float4*)ws;                          // B*M float4 (128 KB)
  size_t off = (size_t)B_ * M_ * sizeof(float4);
  float* csoa = (float*)(ws + off);                     // B*M*4 floats (128 KB)
  off += (size_t)B_ * M_ * 4 * sizeof(float);
  off = (off + 255) & ~(size_t)255;
  unsigned* cand = (unsigned*)(ws + off);               // npts*NCHUNK*4B = 4.2 MB
  off += (npts * (size_t)NCHUNK * 4 + 255) & ~(size_t)255;
  float* fT = (float*)(ws + off);                       // B*M*C floats = 8 MB

  prep_kernel<<<dim3(32 + 2048), dim3(32, 8), 0, stream>>>(
      cxyz, cf, csoa, cpack, fT);
  topk_chunk_kernel<<<dim3(N_ / TOPK_BLOCK, NCHUNK, B_), TOPK_BLOCK, 0, stream>>>(
      xyz, csoa, cand);
  mg_kernel<<<(unsigned)(npts / 4), 256, 0, stream>>>(
      xyz, cpack, cand, fT, out);
}

// Round 15
// 82.563 us; speedup vs baseline: 1.9880x; 1.9880x over previous
//
#include <hip/hip_runtime.h>
#include <math.h>

// Problem constants (fixed by setup_inputs)
constexpr int B_ = 8;
constexpr int N_ = 16384;
constexpr int M_ = 1024;
constexpr int C_ = 256;
constexpr int NCHUNK = 8;
constexpr int CHUNK = M_ / NCHUNK;  // 128
constexpr int KEEP = 4;             // per-chunk survivors
constexpr int TOPK_BLOCK = 1024;    // 16 waves/block -> 2 blocks/CU -> 2 K$ streams

// FINAL LEDGER (all measured):
//   topk ~37us  -- VALUBusy ~100% (R11 amplified-dispatch probe): pure
//                  VALU-issue-bound; 13 instr/pair = 3 pk_fma (distance,
//                  minimal) + 2 v_bfi (index pack) + 8 min/med3 (exact
//                  sorted top-4). pk double-pumps the SIMD-32 ALU (R12).
//   gather ~23us -- 134MB nt-store stream at ~6TB/s write floor; fT reads
//                  L2-resident (R11: marginal read cost ~0).
//   prep+merge ~7.5us -- at traffic/op floors.
//   gaps ~6-9us -- 4 dispatches; every fusion measured costs more than
//                  it saves: R4 grid-collapse, R7 butterfly 7x ops,
//                  R14 few-lane serial 64x issue waste (no-go triangle).
//   R1/R2: role-union kernels poison topk's regalloc (167-183us). Keep
//   the 4-kernel structure.

// native vectors (clang ext_vector): float2 for packed-fp32 math, float4
// for __builtin_nontemporal_store (HIP's float4 class is rejected there).
typedef float f32x2 __attribute__((ext_vector_type(2)));
typedef float nfloat4 __attribute__((ext_vector_type(4)));

// 4-deep sorted-insert network (P0<=P1<=P2<=P3 invariant); valid for any
// non-NaN floats incl. negatives. min + 3x v_med3_f32, all VOP3-legal.
#define INSERT4(P, u)                                              \
  {                                                                \
    const float o0 = P##0, o1 = P##1, o2 = P##2;                   \
    P##0 = fminf(o0, (u));                                         \
    P##1 = __builtin_amdgcn_fmed3f(o0, P##1, (u));                 \
    P##2 = __builtin_amdgcn_fmed3f(o1, P##2, (u));                 \
    P##3 = __builtin_amdgcn_fmed3f(o2, P##3, (u));                 \
  }

// ---------------------------------------------------------------------------
// Kernel 0 (fused prep): blocks [0,32) pack centroids; blocks [32, 32+2048)
// transpose centroid_f [B,C,M] -> fT [B,M,C] via 32x32 LDS tiles (+1 pad).
// ---------------------------------------------------------------------------
__global__ __launch_bounds__(256) void prep_kernel(
    const float* __restrict__ cxyz,  // [B, M, 3]
    const float* __restrict__ cf,    // [B, C, M]
    float* __restrict__ csoa,        // [B][NCHUNK][CHUNK/2][8]
    float4* __restrict__ cpack,      // [B*M]
    float* __restrict__ fT)          // [B, M, C]
{
  __shared__ float tile[32][33];
  const int tx = threadIdx.x;  // 0..31
  const int ty = threadIdx.y;  // 0..7
  if (blockIdx.x < 32) {
    // ---- pack role ----
    const int i = blockIdx.x * 256 + (ty * 32 + tx);  // global centroid id
    if (i < B_ * M_) {
      const int b = i >> 10;         // / M_
      const int m = i & (M_ - 1);
      const int chunk = m >> 7;      // / CHUNK
      const int mi = m & (CHUNK - 1);
      const int pair = mi >> 1;
      const int sub = mi & 1;
      const float x = cxyz[3 * i + 0];
      const float y = cxyz[3 * i + 1];
      const float z = cxyz[3 * i + 2];
      const float w = x * x + y * y + z * z;
      float* pb = csoa + ((((size_t)b * NCHUNK + chunk) * (CHUNK / 2)) + pair) * 8 + sub;
      pb[0] = x; pb[2] = y; pb[4] = z; pb[6] = w;
      cpack[i] = make_float4(x, y, z, w);
    }
  } else {
    // ---- transpose role ----
    const int bid = blockIdx.x - 32;       // 0..2047
    const int m0 = (bid & 31) * 32;        // M/32 = 32
    const int c0 = ((bid >> 5) & 7) * 32;  // C/32 = 8
    const int b = bid >> 8;
    const float* fb = cf + (size_t)b * C_ * M_;
    float* ftb = fT + (size_t)b * M_ * C_;
#pragma unroll
    for (int j = 0; j < 32; j += 8)
      tile[ty + j][tx] = fb[(size_t)(c0 + ty + j) * M_ + (m0 + tx)];
    __syncthreads();
#pragma unroll
    for (int j = 0; j < 32; j += 8)
      ftb[(size_t)(m0 + ty + j) * C_ + (c0 + tx)] = tile[tx][ty + j];
  }
}

// ---------------------------------------------------------------------------
// Kernel 1: chunked top-4 -- R13 (best measured: 82.4us).
//   key = |c|^2 - 2x.c  (3 pk_fma from cw; rank-equivalent to d^2)
//   index pack via v_bfi_b32 (mask VGPR, index SGPR -> 1 SGPR operand)
//   per pair: 3 pk + 2 bfi + 8 min/med3 = 16 equiv-ops.
// DO NOT fuse other roles into this kernel (R1/R2 lesson).
// ---------------------------------------------------------------------------
__global__ __launch_bounds__(TOPK_BLOCK) void topk_chunk_kernel(
    const float* __restrict__ xyz,   // [B, N, 3]
    const float* __restrict__ csoa,  // [B][NCHUNK][CHUNK/2][8]
    unsigned* __restrict__ cand)     // [B*N][NCHUNK]: 4 packed 8-bit indices
{
  const int b = blockIdx.z;
  const int chunk = blockIdx.y;
  const int n = blockIdx.x * TOPK_BLOCK + threadIdx.x;
  const size_t p = (size_t)b * N_ + n;

  const f32x2* __restrict__ cb2 = (const f32x2*)(
      csoa + (((size_t)b * NCHUNK + chunk) * (CHUNK / 2)) * 8);

  const float* xp = xyz + p * 3;
  const float x0 = xp[0], x1 = xp[1], x2 = xp[2];
  const f32x2 nx0_2 = {-2.f * x0, -2.f * x0};
  const f32x2 nx1_2 = {-2.f * x1, -2.f * x1};
  const f32x2 nx2_2 = {-2.f * x2, -2.f * x2};
  unsigned maskv = 0xFFFFFF80u;  // "v"-constrained -> hoisted VGPR constant

  float A0 = INFINITY, A1 = INFINITY, A2 = INFINITY, A3 = INFINITY;
  float B0 = INFINITY, B1 = INFINITY, B2 = INFINITY, B3 = INFINITY;

#pragma unroll 8
  for (int i = 0; i < CHUNK / 2; ++i) {
    // {x0,x1},{y0,y1},{z0,z1},{w0,w1} -- one packed operand per 8B pair
    const f32x2 cx = cb2[i * 4 + 0];
    const f32x2 cy = cb2[i * 4 + 1];
    const f32x2 cz = cb2[i * 4 + 2];
    const f32x2 cw = cb2[i * 4 + 3];

    // key = |c|^2 - 2 x.c  (3 pk_fma; rank-equivalent to d^2 per point)
    f32x2 t = __builtin_elementwise_fma(nx0_2, cx, cw);
    t = __builtin_elementwise_fma(nx1_2, cy, t);
    t = __builtin_elementwise_fma(nx2_2, cz, t);

    // pack 7-bit local index into low mantissa bits: one v_bfi_b32 per key
    unsigned kxu, kyu;
    asm("v_bfi_b32 %0, %1, %2, %3"
        : "=v"(kxu)
        : "v"(maskv), "v"(__float_as_uint(t.x)), "s"((unsigned)(2 * i)));
    asm("v_bfi_b32 %0, %1, %2, %3"
        : "=v"(kyu)
        : "v"(maskv), "v"(__float_as_uint(t.y)), "s"((unsigned)(2 * i + 1)));
    const float kx = __uint_as_float(kxu);
    const float ky = __uint_as_float(kyu);
    INSERT4(A, kx);
    INSERT4(B, ky);
  }
  // fold chain B into chain A (exact running-inserts)
  INSERT4(A, B0);
  INSERT4(A, B1);
  INSERT4(A, B2);
  INSERT4(A, B3);

  const unsigned i0 = __float_as_uint(A0) & 127u;
  const unsigned i1 = __float_as_uint(A1) & 127u;
  const unsigned i2 = __float_as_uint(A2) & 127u;
  const unsigned i3 = __float_as_uint(A3) & 127u;
  cand[p * NCHUNK + chunk] = i0 | (i1 << 8) | (i2 << 16) | (i3 << 24);
}

// ---------------------------------------------------------------------------
// Kernel 2: merge 8x4 candidates -> exact global top-3 + weights. All-lane
// serial scan (f64 re-rank kd = |c|^2 - 2x.c, stable strict-< insertion --
// same expression the quantized keys rank by). Standalone: its ~90-VGPR
// f64 path sets only its own occupancy (R4/R14 lessons).
// ---------------------------------------------------------------------------
__global__ __launch_bounds__(256) void merge_kernel(
    const float* __restrict__ xyz,     // [B, N, 3]
    const float4* __restrict__ cpack,  // [B*M]
    const unsigned* __restrict__ cand, // [B*N][NCHUNK]
    int*   __restrict__ out_idx,       // [B*N, 3]
    float* __restrict__ out_w)         // [B*N, 3]
{
  const size_t p = (size_t)blockIdx.x * 256 + threadIdx.x;
  const int b = (int)(p >> 14);  // p / N_

  const float* xp = xyz + p * 3;
  const double x0d = (double)xp[0], x1d = (double)xp[1], x2d = (double)xp[2];
  const float4* __restrict__ cb = cpack + (size_t)b * M_;

  const uint4* cw4 = (const uint4*)(cand + p * NCHUNK);
  const uint4 ca = cw4[0], cb2 = cw4[1];
  unsigned words[NCHUNK] = {ca.x, ca.y, ca.z, ca.w, cb2.x, cb2.y, cb2.z, cb2.w};

  double D0 = 1e300, D1 = 1e300, D2 = 1e300;
  int I0 = 0, I1 = 0, I2 = 0;
#pragma unroll
  for (int ch = 0; ch < NCHUNK; ++ch) {
    const unsigned w = words[ch];
#pragma unroll
    for (int j = 0; j < KEEP; ++j) {
      const int m = ch * CHUNK + (int)((w >> (8 * j)) & 255u);
      const float4 c = cb[m];
      const double cx = (double)c.x, cy = (double)c.y, cz = (double)c.z;
      const double dot = x0d * cx + x1d * cy + x2d * cz;
      const double c2d = cx * cx + cy * cy + cz * cz;
      const double kd = c2d - 2.0 * dot;
      if (kd < D2) {
        if (kd < D1) {
          D2 = D1; I2 = I1;
          if (kd < D0) { D1 = D0; I1 = I0; D0 = kd; I0 = m; }
          else         { D1 = kd; I1 = m; }
        } else {
          D2 = kd; I2 = m;
        }
      }
    }
  }

  const double xx = x0d * x0d + x1d * x1d + x2d * x2d;
  const float d0 = sqrtf(fmaxf((float)(xx + D0), 0.0f));
  const float d1 = sqrtf(fmaxf((float)(xx + D1), 0.0f));
  const float d2 = sqrtf(fmaxf((float)(xx + D2), 0.0f));
  float w0 = 1.0f / fmaxf(d0, 1e-8f);
  float w1 = 1.0f / fmaxf(d1, 1e-8f);
  float w2 = 1.0f / fmaxf(d2, 1e-8f);
  const float wsum = w0 + w1 + w2;
  w0 /= wsum; w1 /= wsum; w2 /= wsum;

  const size_t o = p * 3;
  out_idx[o + 0] = I0; out_idx[o + 1] = I1; out_idx[o + 2] = I2;
  out_w[o + 0] = w0;   out_w[o + 1] = w1;   out_w[o + 2] = w2;
}

// ---------------------------------------------------------------------------
// Kernel 3: weighted feature gather -- batch<->XCD swizzle (each XCD's L2
// serves one batch's 1MB fT) + non-temporal output stores (134MB stream,
// never re-read). Near its write floor (R11: marginal read cost ~0).
// ---------------------------------------------------------------------------
__global__ __launch_bounds__(256) void gather_kernel(
    const float* __restrict__ fT,   // [B, M, C]
    const int*   __restrict__ idx,  // [B*N, 3]
    const float* __restrict__ w,    // [B*N, 3]
    float* __restrict__ out)        // [B, N, C]
{
  const int wid  = threadIdx.x >> 6;
  const int lane = threadIdx.x & 63;
  // batch<->XCD swizzle: 32768 groups of 4 points; 4096 groups per batch.
  const int g = (blockIdx.x & 7) * 4096 + (blockIdx.x >> 3);
  const size_t p = (size_t)g * 4 + wid;  // global point id
  const int b = (int)(p >> 14);          // p / N_  (== blockIdx.x & 7)

  const size_t o = p * 3;
  const int i0 = idx[o + 0], i1 = idx[o + 1], i2 = idx[o + 2];
  const float w0 = w[o + 0], w1 = w[o + 1], w2 = w[o + 2];

  const float4* f4 = (const float4*)(fT + (size_t)b * M_ * C_);
  float4 a = f4[(size_t)i0 * (C_ / 4) + lane];
  float4 bb = f4[(size_t)i1 * (C_ / 4) + lane];
  float4 c = f4[(size_t)i2 * (C_ / 4) + lane];

  nfloat4 r;
  r.x = w0 * a.x + w1 * bb.x + w2 * c.x;
  r.y = w0 * a.y + w1 * bb.y + w2 * c.y;
  r.z = w0 * a.z + w1 * bb.z + w2 * c.z;
  r.w = w0 * a.w + w1 * bb.w + w2 * c.w;

  __builtin_nontemporal_store(r, &((nfloat4*)out)[p * (C_ / 4) + lane]);
}

extern "C" void kernel_launch(void* const* d_in, const int* in_sizes, int n_in,
                              void* d_out, int out_size, void* d_ws, size_t ws_size,
                              hipStream_t stream) {
  const float* xyz  = (const float*)d_in[0];  // [B, N, 3]
  const float* cxyz = (const float*)d_in[1];  // [B, M, 3]
  const float* cf   = (const float*)d_in[2];  // [B, C, M]
  float* out = (float*)d_out;                 // [B, N, C]

  char* ws = (char*)d_ws;
  const size_t npts = (size_t)B_ * N_;

  int*    idxbuf = (int*)ws;                              // npts*3 ints
  float*  wbuf   = (float*)(ws + npts * 3 * sizeof(int)); // npts*3 floats
  size_t  off    = npts * 3 * 8;
  float4* cpack  = (float4*)(ws + off);                   // B*M float4 (128 KB)
  off += (size_t)B_ * M_ * sizeof(float4);
  float*  csoa   = (float*)(ws + off);                    // B*M*4 floats (128 KB)
  off += (size_t)B_ * M_ * 4 * sizeof(float);
  off = (off + 15) & ~(size_t)15;
  char*   region = ws + off;
  unsigned* cand = (unsigned*)region;  // npts*NCHUNK*4B = 4.2 MB
  size_t cand_bytes = (npts * (size_t)NCHUNK * 4 + 255) & ~(size_t)255;
  float* fT = (float*)(region + cand_bytes);  // B*M*C floats = 8 MB

  prep_kernel<<<dim3(32 + 2048), dim3(32, 8), 0, stream>>>(
      cxyz, cf, csoa, cpack, fT);
  topk_chunk_kernel<<<dim3(N_ / TOPK_BLOCK, NCHUNK, B_), TOPK_BLOCK, 0, stream>>>(
      xyz, csoa, cand);
  merge_kernel<<<(unsigned)(npts / 256), 256, 0, stream>>>(
      xyz, cpack, cand, idxbuf, wbuf);
  gather_kernel<<<(unsigned)(npts / 4), 256, 0, stream>>>(fT, idxbuf, wbuf, out);
}